// Round 1
// baseline (779.625 us; speedup 1.0000x reference)
//
#include <hip/hip_runtime.h>

// PairWiseWeightSmoothLoss — B=64, T=512, V=512, BETA=0.1, PAD=0, normalize by
// count of (target==PAD) positions.
//
// Per position n: loss_n = -[ s*(dot(M,x) - lse*rowsum) + (src - s*M[t])*(x[t]-lse) ]
//   with M = matric[forth[n], tgt[n], :], s = 1 - 0.9^(1/L[b]), src = 1 - s*rowsum.
// One 64-lane wave per position; lane holds 8 elems as two float4 (coalesced 16B/lane).

#define T_DIM 512
#define V_DIM 512
#define LN_0_9 (-0.1053605157f) // ln(0.9)

__global__ __launch_bounds__(256) void pwl_main_kernel(
    const float* __restrict__ input,   // [N, V]
    const int*   __restrict__ target,  // [N]
    const float* __restrict__ length,  // [B]
    const float* __restrict__ matric,  // [V, V, V]
    float*       __restrict__ acc,     // acc[0]=sum(-contrib) fp32, acc[1]=count (uint bits)
    int N)
{
    const int lane = threadIdx.x & 63;
    const int wave = threadIdx.x >> 6;
    const int n = blockIdx.x * 4 + wave;

    __shared__ float    s_num;
    __shared__ unsigned s_cnt;
    if (threadIdx.x == 0) { s_num = 0.0f; s_cnt = 0u; }
    __syncthreads();

    if (n < N) {
        const int t = target[n];
        if (t == 0) {
            if (lane == 0) atomicAdd(&s_cnt, 1u);
        } else {
            const int b  = n / T_DIM;
            const int tp = n % T_DIM;
            const int f  = (tp == 0) ? 0 : target[n - 1];

            // ---- load x row: lane covers v in [4*lane,4*lane+4) and [256+4*lane, ...) ----
            const float4* xrow = (const float4*)(input + (size_t)n * V_DIM);
            const float4 x0 = xrow[lane];
            const float4 x1 = xrow[lane + 64];

            // ---- wave max ----
            float mx = fmaxf(fmaxf(fmaxf(x0.x, x0.y), fmaxf(x0.z, x0.w)),
                             fmaxf(fmaxf(x1.x, x1.y), fmaxf(x1.z, x1.w)));
            #pragma unroll
            for (int off = 32; off > 0; off >>= 1)
                mx = fmaxf(mx, __shfl_xor(mx, off, 64));

            // ---- wave sum exp(x - mx) ----
            float se = expf(x0.x - mx) + expf(x0.y - mx) + expf(x0.z - mx) + expf(x0.w - mx)
                     + expf(x1.x - mx) + expf(x1.y - mx) + expf(x1.z - mx) + expf(x1.w - mx);
            #pragma unroll
            for (int off = 32; off > 0; off >>= 1)
                se += __shfl_xor(se, off, 64);
            const float lse = mx + logf(se);

            // ---- gathered confusion row ----
            const float4* mrow = (const float4*)(matric + ((size_t)f * V_DIM + t) * V_DIM);
            const float4 m0 = mrow[lane];
            const float4 m1 = mrow[lane + 64];

            float dot = m0.x * x0.x + m0.y * x0.y + m0.z * x0.z + m0.w * x0.w
                      + m1.x * x1.x + m1.y * x1.y + m1.z * x1.z + m1.w * x1.w;
            float rs  = m0.x + m0.y + m0.z + m0.w + m1.x + m1.y + m1.z + m1.w;

            // ---- pick out M[t], x[t] (exactly one lane hits) ----
            float Mt = 0.0f, xt = 0.0f;
            {
                const float mv0[4] = {m0.x, m0.y, m0.z, m0.w};
                const float xv0[4] = {x0.x, x0.y, x0.z, x0.w};
                const float mv1[4] = {m1.x, m1.y, m1.z, m1.w};
                const float xv1[4] = {x1.x, x1.y, x1.z, x1.w};
                int d0 = t - 4 * lane;
                if ((unsigned)d0 < 4u) { Mt = mv0[d0]; xt = xv0[d0]; }
                int d1 = t - (256 + 4 * lane);
                if ((unsigned)d1 < 4u) { Mt = mv1[d1]; xt = xv1[d1]; }
            }

            #pragma unroll
            for (int off = 32; off > 0; off >>= 1) {
                dot += __shfl_xor(dot, off, 64);
                rs  += __shfl_xor(rs,  off, 64);
                Mt  += __shfl_xor(Mt,  off, 64);
                xt  += __shfl_xor(xt,  off, 64);
            }

            if (lane == 0) {
                const float L = length[b];
                const float s = 1.0f - expf(LN_0_9 / L);   // 1 - 0.9^(1/L)
                const float src = 1.0f - s * rs;
                const float contrib = s * (dot - lse * rs) + (src - s * Mt) * (xt - lse);
                atomicAdd(&s_num, -contrib);
            }
        }
    }

    __syncthreads();
    if (threadIdx.x == 0) {
        atomicAdd(&acc[0], s_num);
        atomicAdd((unsigned*)acc + 1, s_cnt);
    }
}

__global__ void pwl_final_kernel(const float* __restrict__ acc, float* __restrict__ out)
{
    const unsigned cnt = ((const unsigned*)acc)[1];
    out[0] = acc[0] / (float)cnt;
}

extern "C" void kernel_launch(void* const* d_in, const int* in_sizes, int n_in,
                              void* d_out, int out_size, void* d_ws, size_t ws_size,
                              hipStream_t stream) {
    const float* input  = (const float*)d_in[0];
    const int*   target = (const int*)  d_in[1];
    const float* length = (const float*)d_in[2];
    const float* matric = (const float*)d_in[3];
    float* out = (float*)d_out;
    float* acc = (float*)d_ws;

    const int N = in_sizes[1];          // B*T = 32768

    hipMemsetAsync(acc, 0, 2 * sizeof(float), stream);

    const int blocks = (N + 3) / 4;     // 4 waves (positions) per 256-thread block
    pwl_main_kernel<<<blocks, 256, 0, stream>>>(input, target, length, matric, acc, N);
    pwl_final_kernel<<<1, 1, 0, stream>>>(acc, out);
}